// Round 4
// baseline (415.624 us; speedup 1.0000x reference)
//
#include <hip/hip_runtime.h>
#include <hip/hip_bf16.h>

// BNN MC-prediction: S=100 weight samples, batch 64, dims 784->512->512->10.
// R4: page-dense eps access. R1-R3 all plateaued at ~920 GB/s regardless of
// load width / barriers / chunk size (64-256 B per 4-KiB page visit) ->
// translation-walk-limited. Fix: BN=512 blocks (16 waves x 32n) read FULL
// 2-KB eps rows, each page walked once per block. K split so grid = 256
// blocks = exactly 1 per CU (56 samples x 3 chunks + 44 x 2). fp32 partials
// reduced by a streaming bias+relu kernel.

typedef __bf16 bf16x8 __attribute__((ext_vector_type(8)));
typedef float f32x4 __attribute__((ext_vector_type(4)));

#define NSAMP 100
#define BATCH 64
#define D0 784
#define D1 512
#define D2 512
#define DOUT 10
#define K0PAD 800   // 784 padded to x32 (A side zero-padded)
#define RSB 40      // LDS row stride in shorts (80 B: 16B-aligned b128 reads)
#define S3 56       // samples with 3 k-chunks (56*3 + 44*2 = 256 blocks)

__device__ __forceinline__ unsigned short f2bf(float f) {
    __bf16 b = (__bf16)f;
    return __builtin_bit_cast(unsigned short, b);
}
__device__ __forceinline__ float bf_hi(unsigned int u) {
    return __builtin_bit_cast(float, u & 0xffff0000u);
}
__device__ __forceinline__ float bf_lo(unsigned int u) {
    return __builtin_bit_cast(float, u << 16);
}

union FragU { uint4 q; uint2 d[2]; bf16x8 v; };

// ---------------- precompute ----------------
#define XB_N   (BATCH * K0PAD)
#define PS0_N  (D0 * D1)
#define PS1_N  (D1 * D2)
#define SGL_N  (D2 * DOUT)
#define B0_N   (NSAMP * D1)
#define B1_N   (NSAMP * D2)
#define BL_N   (NSAMP * DOUT)
#define PREP_TOTAL (XB_N + PS0_N + PS1_N + SGL_N + B0_N + B1_N + BL_N)

__global__ __launch_bounds__(256) void prep(
    const float* __restrict__ inputs,
    const float* __restrict__ wv0, const float* __restrict__ wm0,
    const float* __restrict__ wv1, const float* __restrict__ wm1,
    const float* __restrict__ wvl,
    const float* __restrict__ be0, const float* __restrict__ bv0, const float* __restrict__ bm0,
    const float* __restrict__ be1, const float* __restrict__ bv1, const float* __restrict__ bm1,
    const float* __restrict__ bel, const float* __restrict__ bvl, const float* __restrict__ bml,
    unsigned short* __restrict__ Xb,
    unsigned int* __restrict__ psm0, unsigned int* __restrict__ psm1,
    float* __restrict__ sigmal,
    float* __restrict__ bias0, float* __restrict__ bias1, float* __restrict__ biasl)
{
    int i = blockIdx.x * 256 + threadIdx.x;
    if (i < XB_N) {
        int m = i / K0PAD, k = i % K0PAD;
        float v = (k < D0) ? inputs[m * D0 + k] : 0.f;
        Xb[i] = f2bf(v);
        return;
    }
    i -= XB_N;
    if (i < PS0_N) {
        unsigned int sg = f2bf(__expf(0.5f * wv0[i]));
        unsigned int mn = f2bf(wm0[i]);
        psm0[i] = (sg << 16) | mn;
        return;
    }
    i -= PS0_N;
    if (i < PS1_N) {
        unsigned int sg = f2bf(__expf(0.5f * wv1[i]));
        unsigned int mn = f2bf(wm1[i]);
        psm1[i] = (sg << 16) | mn;
        return;
    }
    i -= PS1_N;
    if (i < SGL_N) { sigmal[i] = __expf(0.5f * wvl[i]); return; }
    i -= SGL_N;
    if (i < B0_N) { int n = i % D1; bias0[i] = fmaf(be0[i], __expf(0.5f * bv0[n]), bm0[n]); return; }
    i -= B0_N;
    if (i < B1_N) { int n = i % D2; bias1[i] = fmaf(be1[i], __expf(0.5f * bv1[n]), bm1[n]); return; }
    i -= B1_N;
    if (i < BL_N) { int o = i % DOUT; biasl[i] = fmaf(bel[i], __expf(0.5f * bvl[o]), bml[o]); return; }
}

// ---------------- page-dense fused-sampling GEMM ----------------
// Block = 1024 threads = 16 waves; wave w computes 64(M) x 32(N) at n0=32w.
// Block covers the FULL n=512 row width -> every eps page read densely, once.
// Grid = 256: samples 0..55 get 3 k-chunks, 56..99 get 2.
__global__ __launch_bounds__(1024) void gemm_full(
    const unsigned short* __restrict__ A, int lda, long aStride,  // bf16 [.][64][lda]
    const float* __restrict__ eps, long eStride,                  // fp32 [S][Kvalid][512]
    const unsigned int* __restrict__ psm,                         // packed [Kvalid][512]
    int KTtotal, int Kvalid,
    float* __restrict__ partial)                                  // [S][3][64][512] fp32
{
    __shared__ unsigned short smB[16 * 32 * RSB];   // 40 KB

    const int b = blockIdx.x;
    int s, c, ks;
    if (b < S3 * 3) { s = b / 3; c = b - 3 * s; ks = 3; }
    else            { int t = b - S3 * 3; s = S3 + (t >> 1); c = t & 1; ks = 2; }
    const int base = KTtotal / ks, rem = KTtotal % ks;
    const int kt0 = c * base + (c < rem ? c : rem);
    const int ktn = base + (c < rem ? 1 : 0);

    const int w    = threadIdx.x >> 6;
    const int lane = threadIdx.x & 63;
    const int fr = lane & 15, quad = lane >> 4;
    const int kg = lane >> 3, ng = lane & 7;
    const int n0 = w << 5;

    const unsigned short* aP = A + (long)s * aStride + (long)fr * lda + quad * 8;
    const float* eB        = eps + (long)s * eStride + n0 + 4 * ng;
    const unsigned int* pB = psm + n0 + 4 * ng;
    unsigned short* smW = &smB[w * 32 * RSB];

    f32x4 acc[4][2] = {};

    for (int kt = kt0; kt < kt0 + ktn; ++kt) {
        const int kb = kt * 32;
        __syncthreads();                       // smB free
        uint4 aa[4];
#pragma unroll
        for (int mi = 0; mi < 4; ++mi)
            aa[mi] = *reinterpret_cast<const uint4*>(aP + (long)(mi * 16) * lda + kb);
        float4 e[4]; uint4 p[4];
#pragma unroll
        for (int j = 0; j < 4; ++j) {
            const int row = kb + 4 * kg + j;
            const bool okr = row < Kvalid;
            const long off = (long)(okr ? row : 0) * 512;
            float4 ev = *reinterpret_cast<const float4*>(eB + off);
            uint4  pv = *reinterpret_cast<const uint4*>(pB + off);
            if (!okr) { ev = float4{0.f,0.f,0.f,0.f}; pv = uint4{0u,0u,0u,0u}; }
            e[j] = ev; p[j] = pv;
        }
        // transform (eps*sigma+mean -> bf16) + in-register transpose -> LDS [n][k]
        {
            float t[4][4];   // t[j][i] = W[k=4kg+j][n=4ng+i]
#pragma unroll
            for (int j = 0; j < 4; ++j) {
                t[j][0] = fmaf(e[j].x, bf_hi(p[j].x), bf_lo(p[j].x));
                t[j][1] = fmaf(e[j].y, bf_hi(p[j].y), bf_lo(p[j].y));
                t[j][2] = fmaf(e[j].z, bf_hi(p[j].z), bf_lo(p[j].z));
                t[j][3] = fmaf(e[j].w, bf_hi(p[j].w), bf_lo(p[j].w));
            }
#pragma unroll
            for (int i = 0; i < 4; ++i) {
                uint2 d;
                d.x = (unsigned)f2bf(t[0][i]) | ((unsigned)f2bf(t[1][i]) << 16);
                d.y = (unsigned)f2bf(t[2][i]) | ((unsigned)f2bf(t[3][i]) << 16);
                *reinterpret_cast<uint2*>(&smW[(4 * ng + i) * RSB + 4 * kg]) = d;
            }
        }
        __syncthreads();                       // smB ready
        FragU bf0, bf1;
        bf0.q = *reinterpret_cast<const uint4*>(&smW[fr * RSB + quad * 8]);
        bf1.q = *reinterpret_cast<const uint4*>(&smW[(16 + fr) * RSB + quad * 8]);
#pragma unroll
        for (int mi = 0; mi < 4; ++mi) {
            FragU af; af.q = aa[mi];
            acc[mi][0] = __builtin_amdgcn_mfma_f32_16x16x32_bf16(af.v, bf0.v, acc[mi][0], 0, 0, 0);
            acc[mi][1] = __builtin_amdgcn_mfma_f32_16x16x32_bf16(af.v, bf1.v, acc[mi][1], 0, 0, 0);
        }
    }

    // store fp32 partial (bias/relu applied in reduce)
    float* out = partial + ((long)s * 3 + c) * (64 * 512);
#pragma unroll
    for (int mi = 0; mi < 4; ++mi)
#pragma unroll
        for (int ni = 0; ni < 2; ++ni)
#pragma unroll
            for (int r = 0; r < 4; ++r) {
                const int row = mi * 16 + quad * 4 + r;
                const int col = n0 + ni * 16 + fr;
                out[(long)row * 512 + col] = acc[mi][ni][r];
            }
}

// ---------------- reduce partials + bias + relu + optional bf16 cast ---------
__global__ __launch_bounds__(256) void reduce_bias_relu(
    const float* __restrict__ partial,  // [S][3][64][512]
    const float* __restrict__ bias,     // [S][512]
    void* __restrict__ outp, int outBf16)  // [S][64][512]
{
    const long total4 = (long)NSAMP * 64 * 512 / 4;
    long i4 = (long)blockIdx.x * 256 + threadIdx.x;
    if (i4 >= total4) return;
    const long e0 = i4 * 4;
    const int s    = (int)(e0 >> 15);        // / 32768
    const int in_s = (int)(e0 & 32767);
    const int n    = in_s & 511;
    const int ks   = (s < S3) ? 3 : 2;

    const float* p = partial + (long)s * 3 * 32768 + in_s;
    float4 v  = *reinterpret_cast<const float4*>(p);
    float4 v1 = *reinterpret_cast<const float4*>(p + 32768);
    v.x += v1.x; v.y += v1.y; v.z += v1.z; v.w += v1.w;
    if (ks == 3) {
        float4 v2 = *reinterpret_cast<const float4*>(p + 65536);
        v.x += v2.x; v.y += v2.y; v.z += v2.z; v.w += v2.w;
    }
    const float4 bv = *reinterpret_cast<const float4*>(bias + (long)s * 512 + n);
    v.x = fmaxf(v.x + bv.x, 0.f);
    v.y = fmaxf(v.y + bv.y, 0.f);
    v.z = fmaxf(v.z + bv.z, 0.f);
    v.w = fmaxf(v.w + bv.w, 0.f);
    if (outBf16) {
        uint2 d;
        d.x = (unsigned)f2bf(v.x) | ((unsigned)f2bf(v.y) << 16);
        d.y = (unsigned)f2bf(v.z) | ((unsigned)f2bf(v.w) << 16);
        reinterpret_cast<uint2*>(outp)[i4] = d;
    } else {
        reinterpret_cast<float4*>(outp)[i4] = v;
    }
}

// ---------------- final layer: [64,512] @ [512,10] + bias, fp32 VALU ----------
__global__ __launch_bounds__(320) void last_layer(
    const float* __restrict__ act2,   // [S][64][512]
    const float* __restrict__ wel,    // [S][512][10]
    const float* __restrict__ sigmal, // [512][10]
    const float* __restrict__ wml,    // [512][10]
    const float* __restrict__ biasl,  // [S][10]
    float* __restrict__ out)          // [S][64][10]
{
    __shared__ float smW[D2 * DOUT];  // 20 KB
    const int s = blockIdx.x;
    const int t = threadIdx.x;
    const float* we = wel + (long)s * D2 * DOUT;
    for (int i = t; i < D2 * DOUT; i += 320)
        smW[i] = fmaf(we[i], sigmal[i], wml[i]);
    __syncthreads();

    const int m  = t / 5;
    const int op = t % 5;
    const float* a = act2 + ((long)s * BATCH + m) * D2;
    float acc0 = 0.f, acc1 = 0.f;
#pragma unroll 4
    for (int k = 0; k < D2; k += 4) {
        float4 av = *reinterpret_cast<const float4*>(a + k);
        acc0 = fmaf(av.x, smW[(k + 0) * DOUT + op], acc0);
        acc0 = fmaf(av.y, smW[(k + 1) * DOUT + op], acc0);
        acc0 = fmaf(av.z, smW[(k + 2) * DOUT + op], acc0);
        acc0 = fmaf(av.w, smW[(k + 3) * DOUT + op], acc0);
        acc1 = fmaf(av.x, smW[(k + 0) * DOUT + op + 5], acc1);
        acc1 = fmaf(av.y, smW[(k + 1) * DOUT + op + 5], acc1);
        acc1 = fmaf(av.z, smW[(k + 2) * DOUT + op + 5], acc1);
        acc1 = fmaf(av.w, smW[(k + 3) * DOUT + op + 5], acc1);
    }
    const long ob = ((long)s * BATCH + m) * DOUT;
    out[ob + op]     = acc0 + biasl[s * DOUT + op];
    out[ob + op + 5] = acc1 + biasl[s * DOUT + op + 5];
}

extern "C" void kernel_launch(void* const* d_in, const int* in_sizes, int n_in,
                              void* d_out, int out_size, void* d_ws, size_t ws_size,
                              hipStream_t stream)
{
    const float* inputs = (const float*)d_in[0];
    // d_in[1] = task_id (unused)
    const float* wm0 = (const float*)d_in[2];
    const float* wv0 = (const float*)d_in[3];
    const float* bm0 = (const float*)d_in[4];
    const float* bv0 = (const float*)d_in[5];
    const float* wm1 = (const float*)d_in[6];
    const float* wv1 = (const float*)d_in[7];
    const float* bm1 = (const float*)d_in[8];
    const float* bv1 = (const float*)d_in[9];
    const float* wml = (const float*)d_in[10];
    const float* wvl = (const float*)d_in[11];
    const float* bml = (const float*)d_in[12];
    const float* bvl = (const float*)d_in[13];
    const float* we0 = (const float*)d_in[14];
    const float* be0 = (const float*)d_in[15];
    const float* we1 = (const float*)d_in[16];
    const float* be1 = (const float*)d_in[17];
    const float* wel = (const float*)d_in[18];
    const float* bel = (const float*)d_in[19];

    // workspace carve (~62 MB, 16B-aligned chunks)
    char* w = (char*)d_ws;
    unsigned short* Xb  = (unsigned short*)w; w += (size_t)XB_N * 2;
    unsigned int* psm0  = (unsigned int*)w;   w += (size_t)PS0_N * 4;
    unsigned int* psm1  = (unsigned int*)w;   w += (size_t)PS1_N * 4;
    float* sigmal = (float*)w; w += (size_t)SGL_N * 4;
    float* bias0  = (float*)w; w += (size_t)B0_N * 4;
    float* bias1  = (float*)w; w += (size_t)B1_N * 4;
    float* biasl  = (float*)w; w += (size_t)BL_N * 4;
    unsigned short* act1 = (unsigned short*)w; w += (size_t)NSAMP * BATCH * D1 * 2;
    float* act2    = (float*)w; w += (size_t)NSAMP * BATCH * D2 * 4;
    float* partial = (float*)w; w += (size_t)NSAMP * 3 * BATCH * 512 * 4;  // shared by both layers

    prep<<<dim3((PREP_TOTAL + 255) / 256), 256, 0, stream>>>(
        inputs, wv0, wm0, wv1, wm1, wvl,
        be0, bv0, bm0, be1, bv1, bm1, bel, bvl, bml,
        Xb, psm0, psm1, sigmal, bias0, bias1, biasl);

    const int RED_GRID = (NSAMP * BATCH * 512 / 4 + 255) / 256;

    // layer 0: A = Xb shared (aStride=0), KT=25 (K0PAD), Kvalid=784
    gemm_full<<<dim3(256), 1024, 0, stream>>>(
        Xb, K0PAD, 0L, we0, (long)D0 * D1, psm0, K0PAD / 32, D0, partial);
    reduce_bias_relu<<<dim3(RED_GRID), 256, 0, stream>>>(
        partial, bias0, (void*)act1, 1);

    // layer 1: A = act1, KT=16, Kvalid=512
    gemm_full<<<dim3(256), 1024, 0, stream>>>(
        act1, D1, (long)BATCH * D1, we1, (long)D1 * D2, psm1, D1 / 32, D1, partial);
    reduce_bias_relu<<<dim3(RED_GRID), 256, 0, stream>>>(
        partial, bias1, (void*)act2, 0);

    last_layer<<<dim3(NSAMP), 320, 0, stream>>>(
        act2, wel, sigmal, wml, biasl, (float*)d_out);
}